// Round 8
// baseline (522.863 us; speedup 1.0000x reference)
//
#include <hip/hip_runtime.h>
#include <math.h>

#define DIMX 50
#define KK   51
#define NE   6
#define NB   8
#define NVOX ((size_t)NB * NE * DIMX * DIMX * DIMX)  // 6,000,000
#define MP   52                                      // padded M stride

// ---------------- taps + blur matrices: M[m][e][o][c] = tap_m,e[c-o+25] ----------------
__global__ void taps_kernel(const float* __restrict__ sigma,
                            float* __restrict__ M0,  // raw taps matrix  (NE*52*52)
                            float* __restrict__ M1,  // scaled taps matrix
                            float* __restrict__ maxval) {
    __shared__ float sg[NE * KK];
    __shared__ float sgs[NE * KK];
    __shared__ float ssum[NE];
    int t = threadIdx.x;
    if (t == 0) *maxval = 0.f;
    if (t < NE * KK) {
        int e = t / KK, i = t % KK;
        float d = (float)i - 25.0f;
        float var = sigma[e] * sigma[e];
        sg[t] = expf(-d * d / (2.f * var));
    }
    __syncthreads();
    if (t < NE) {
        float s = 0.f;
        for (int i = 0; i < KK; ++i) s += sg[t * KK + i];
        ssum[t] = s;
    }
    __syncthreads();
    if (t < NE * KK) {
        int e = t / KK;
        float S = 0.f;
        for (int e2 = 0; e2 < NE; ++e2) {
            float var2 = sigma[e2] * sigma[e2];
            float a2 = 1.f / (2.f * (float)M_PI * var2);
            float se = ssum[e2];
            S += a2 * se * se * se;
        }
        float var = sigma[e] * sigma[e];
        float a = 1.f / (2.f * (float)M_PI * var);
        sgs[t] = sg[t] * (a / S);
    }
    __syncthreads();
    for (int i = t; i < 2 * NE * MP * MP; i += 512) {
        int c = i % MP, o = (i / MP) % MP, e = (i / (MP * MP)) % NE, m = i / (MP * MP * NE);
        int j = c - o + 25;
        float v = 0.f;
        if (o < 50 && c < 50 && j >= 0 && j < KK) v = (m == 0 ? sg : sgs)[e * KK + j];
        (m == 0 ? M0 : M1)[(e * MP + o) * MP + c] = v;
    }
}

// ---------------- blur pass as per-plane 50x50 matmul ----------------
template <int AXIS, bool DOMAX>
__global__ __launch_bounds__(256, 8)
void blur_mm(const float* __restrict__ in, float* __restrict__ out,
             const float* __restrict__ M, float* __restrict__ maxval) {
    __shared__ float sp[50][MP];
    const int t  = threadIdx.x;
    const int f  = blockIdx.x % 50;
    const int be = blockIdx.x / 50;
    const int e  = be % NE;
    const float* base = in + (size_t)be * 125000;
    for (int i = t; i < 2500; i += 256) {
        int hi = i / 50, lo = i % 50;
        if (AXIS == 2)      sp[hi][lo] = base[hi * 2500 + f * 50 + lo];
        else if (AXIS == 1) sp[hi][lo] = base[f * 2500 + hi * 50 + lo];
        else                sp[lo][hi] = base[f * 2500 + hi * 50 + lo];
    }
    __syncthreads();
    const int lane = t & 63;
    const int lr   = lane < 50 ? lane : 49;
    const int wv   = __builtin_amdgcn_readfirstlane(t >> 6);
    float* ob = out + (size_t)be * 125000;
    const float* Me = M + (size_t)e * MP * MP;
    float m = 0.f;
    for (int g = wv; g < 13; g += 4) {
        const int o0 = g * 4;
        const float* Mr0 = Me + (o0 + 0) * MP;
        const float* Mr1 = Me + (o0 + 1) * MP;
        const float* Mr2 = Me + (o0 + 2) * MP;
        const float* Mr3 = Me + (o0 + 3) * MP;
        float a0 = 0.f, a1 = 0.f, a2 = 0.f, a3 = 0.f;
#pragma unroll 10
        for (int c = 0; c < 50; ++c) {
            float v = sp[c][lr];
            a0 = fmaf(Mr0[c], v, a0);
            a1 = fmaf(Mr1[c], v, a1);
            a2 = fmaf(Mr2[c], v, a2);
            a3 = fmaf(Mr3[c], v, a3);
        }
        if (lane < 50) {
            float accs[4] = {a0, a1, a2, a3};
#pragma unroll
            for (int k = 0; k < 4; ++k) {
                int o = o0 + k;
                if (o < 50) {
                    size_t addr;
                    if (AXIS == 2)      addr = (size_t)o * 2500 + f * 50 + lane;
                    else if (AXIS == 1) addr = (size_t)f * 2500 + o * 50 + lane;
                    else                addr = (size_t)f * 2500 + lane * 50 + o;
                    ob[addr] = accs[k];
                    if (DOMAX) m = fmaxf(m, accs[k]);
                }
            }
        }
    }
    if (DOMAX) {
        for (int o = 32; o; o >>= 1) m = fmaxf(m, __shfl_xor(m, o));
        if ((t & 63) == 0) atomicMax((int*)maxval, __float_as_int(m));
    }
}

// ---------------- fused conv3x3x3 [+pool2+bias+relu | partial], COPT co/thread ----------------
// Block: 4^3 pooled tile x (4*COPT) co (4 waves x COPT co each). NCI channels staged per
// phase via global_load_lds, double-buffered across phases. LDS window [z][y][e/o][6].
// Weights wave-uniform scalar loads.
template <int COPT, int NCI, int NPHASE, int CINTOT, int DIN, int DP, bool DIV, bool PARTIAL>
__global__ __launch_bounds__(256, 4)
void conv_phase(const float* __restrict__ in, const float* __restrict__ w,
                const float* __restrict__ bias, const float* __restrict__ maxval,
                float* __restrict__ out, int COUT) {
    constexpr int DIN3 = DIN * DIN * DIN;
    constexpr int NT   = (DP + 3) / 4;
    constexpr int NT3  = NT * NT * NT;
    constexpr int CWORDS = 1200;             // [10][10][12] per ci
    constexpr int NBUF = (NPHASE > 1) ? 2 : 1;
    __shared__ float swin[NBUF][NCI * CWORDS];

    const int t    = threadIdx.x;
    const int lane = t & 63;
    const int wave = __builtin_amdgcn_readfirstlane(t >> 6);
    const int px = lane & 3, py = (lane >> 2) & 3, pz = lane >> 4;

    const int tile  = blockIdx.x % NT3;
    const int chunk = blockIdx.x / NT3;
    const int tx = tile % NT, ty = (tile / NT) % NT, tz = tile / (NT * NT);
    const int b    = blockIdx.z;
    const int co0  = blockIdx.y * (4 * COPT) + wave * COPT;   // wave-uniform
    const int ci_base = chunk * NCI * NPHASE;

    const float* ib = in + ((size_t)b * CINTOT + ci_base) * DIN3;
    const float* wb = w + ((size_t)co0 * CINTOT + ci_base) * 27;
    const int ox0 = 8 * tx, oy0 = 8 * ty, oz0 = 8 * tz;

    // per-thread source offsets; LDS dest linear j = s*256 + t, source pre-permuted
    int off[5];
#pragma unroll
    for (int s = 0; s < 5; ++s) {
        int j = s * 256 + t; if (j >= CWORDS) j = CWORDS - 1;
        int z = j / 120, r = j % 120, y = r / 12, q = r % 12;
        int x = 2 * (q % 6) + q / 6; if (x > 9) x = 9;   // e/o split
        int gz = oz0 + z; if (gz > DIN - 1) gz = DIN - 1;
        int gy = oy0 + y; if (gy > DIN - 1) gy = DIN - 1;
        int gx = ox0 + x; if (gx > DIN - 1) gx = DIN - 1;
        off[s] = (gz * DIN + gy) * DIN + gx;
    }

    auto stage = [&](int p, int bf) {
        const float* s0 = ib + (size_t)p * NCI * DIN3;
#pragma unroll
        for (int ci = 0; ci < NCI; ++ci) {
            const float* sc = s0 + (size_t)ci * DIN3;
            float* db = &swin[bf][ci * CWORDS];
#pragma unroll
            for (int s = 0; s < 4; ++s)
                __builtin_amdgcn_global_load_lds(
                    (const __attribute__((address_space(1))) void*)(sc + off[s]),
                    (__attribute__((address_space(3))) void*)(db + s * 256 + wave * 64),
                    4, 0, 0);
            if (t < CWORDS - 1024)
                __builtin_amdgcn_global_load_lds(
                    (const __attribute__((address_space(1))) void*)(sc + off[4]),
                    (__attribute__((address_space(3))) void*)(db + 1024 + wave * 64),
                    4, 0, 0);
        }
    };

    float acc[COPT][8];
#pragma unroll
    for (int c = 0; c < COPT; ++c)
#pragma unroll
        for (int i = 0; i < 8; ++i) acc[c][i] = 0.f;

    stage(0, 0);
    __syncthreads();

#pragma unroll 1
    for (int p = 0; p < NPHASE; ++p) {
        if (p + 1 < NPHASE) stage(p + 1, (p + 1) & 1);
        const float* pb = &swin[(NBUF > 1) ? (p & 1) : 0][0];
#pragma unroll 1
        for (int ci = 0; ci < NCI; ++ci) {
            const float* cb = pb + ci * CWORDS;
#pragma unroll
            for (int dz = 0; dz < 4; ++dz) {
                const float* sb = cb + (2 * pz + dz) * 120 + (2 * py) * 12 + px;
                float sl[4][4];
#pragma unroll
                for (int dy = 0; dy < 4; ++dy) {
                    sl[dy][0] = sb[dy * 12];
                    sl[dy][1] = sb[dy * 12 + 6];
                    sl[dy][2] = sb[dy * 12 + 1];
                    sl[dy][3] = sb[dy * 12 + 7];
                }
#pragma unroll
                for (int c = 0; c < COPT; ++c) {
#pragma unroll
                    for (int oz = 0; oz < 2; ++oz) {
                        const int kz = dz - oz;
                        if (kz < 0 || kz > 2) continue;
                        const float* wc = wb + ((size_t)c * CINTOT + p * NCI + ci) * 27 + kz * 9;
#pragma unroll
                        for (int ky = 0; ky < 3; ++ky)
#pragma unroll
                            for (int kx = 0; kx < 3; ++kx) {
                                float wv = wc[ky * 3 + kx];
#pragma unroll
                                for (int oy = 0; oy < 2; ++oy)
#pragma unroll
                                    for (int ox = 0; ox < 2; ++ox)
                                        acc[c][oz * 4 + oy * 2 + ox] =
                                            fmaf(wv, sl[oy + ky][ox + kx],
                                                 acc[c][oz * 4 + oy * 2 + ox]);
                            }
                    }
                }
            }
        }
        __syncthreads();
    }

    if constexpr (PARTIAL) {
#pragma unroll
        for (int c = 0; c < COPT; ++c) {
            size_t base = (((size_t)chunk * NB + b) * (size_t)COUT + (co0 + c)) * 512 + (size_t)lane * 8;
#pragma unroll
            for (int i = 0; i < 8; ++i) out[base + i] = acc[c][i];
        }
    } else {
        const int qx = tx * 4 + px, qy = ty * 4 + py, qz = tz * 4 + pz;
        if (qx < DP && qy < DP && qz < DP) {
            float mv = DIV ? *maxval : 1.f;
#pragma unroll
            for (int c = 0; c < COPT; ++c) {
                float m = acc[c][0];
#pragma unroll
                for (int i = 1; i < 8; ++i) m = fmaxf(m, acc[c][i]);
                float o = DIV ? (m / mv + bias[co0 + c]) : (m + bias[co0 + c]);
                out[((size_t)b * COUT + (co0 + c)) * (DP * DP * DP) + (qz * DP + qy) * DP + qx] =
                    fmaxf(o, 0.f);
            }
        }
    }
}

// ---------------- conv3 chunk-reduce + pool + bias + relu ----------------
template <int NCH>
__global__ void pool3_kernel(const float* __restrict__ part, const float* __restrict__ bias,
                             float* __restrict__ out) {
    int idx = blockIdx.x * 256 + threadIdx.x;  // 8*128*64
    if (idx >= NB * 128 * 64) return;
    int vox = idx & 63;
    int co  = (idx >> 6) & 127;
    int b   = idx >> 13;
    float s[8];
#pragma unroll
    for (int i = 0; i < 8; ++i) s[i] = 0.f;
#pragma unroll
    for (int ch = 0; ch < NCH; ++ch) {
        const float* p = part + (((size_t)ch * NB + b) * 128 + co) * 512 + (size_t)vox * 8;
#pragma unroll
        for (int i = 0; i < 8; ++i) s[i] += p[i];
    }
    float m = s[0];
#pragma unroll
    for (int i = 1; i < 8; ++i) m = fmaxf(m, s[i]);
    out[((size_t)b * 128 + co) * 64 + vox] = fmaxf(m + bias[co], 0.f);
}

// ---------------- conv4: Cin=128, Din=4 -> conv 2^3 -> pool 1; wave per (b,co) ----------------
__global__ void conv4_kernel(const float* __restrict__ in, const float* __restrict__ w,
                             const float* __restrict__ bias, float* __restrict__ out) {
    int wid = (int)((blockIdx.x * blockDim.x + threadIdx.x) >> 6);
    int lane = threadIdx.x & 63;
    if (wid >= NB * 256) return;
    int b = wid >> 8, co = wid & 255;
    float acc[8];
#pragma unroll
    for (int i = 0; i < 8; ++i) acc[i] = 0.f;
    for (int half = 0; half < 2; ++half) {
        int ci = lane + half * 64;
        const float* cb = in + ((size_t)b * 128 + ci) * 64;
        float win[64];
        const float4* c4 = (const float4*)cb;
#pragma unroll
        for (int i = 0; i < 16; ++i) {
            float4 v = c4[i];
            win[4 * i + 0] = v.x; win[4 * i + 1] = v.y;
            win[4 * i + 2] = v.z; win[4 * i + 3] = v.w;
        }
        const float* wc = w + ((size_t)co * 128 + ci) * 27;
        float wr[27];
#pragma unroll
        for (int i = 0; i < 27; ++i) wr[i] = wc[i];
#pragma unroll
        for (int kz = 0; kz < 3; ++kz)
#pragma unroll
            for (int ky = 0; ky < 3; ++ky)
#pragma unroll
                for (int kx = 0; kx < 3; ++kx) {
                    float wv = wr[(kz * 3 + ky) * 3 + kx];
#pragma unroll
                    for (int oz = 0; oz < 2; ++oz)
#pragma unroll
                        for (int oy = 0; oy < 2; ++oy)
#pragma unroll
                            for (int ox = 0; ox < 2; ++ox)
                                acc[(oz * 2 + oy) * 2 + ox] =
                                    fmaf(wv, win[((oz + kz) * 4 + (oy + ky)) * 4 + ox + kx],
                                         acc[(oz * 2 + oy) * 2 + ox]);
                }
    }
#pragma unroll
    for (int o = 32; o; o >>= 1)
#pragma unroll
        for (int i = 0; i < 8; ++i) acc[i] += __shfl_xor(acc[i], o);
    if (lane == 0) {
        float m = acc[0];
#pragma unroll
        for (int i = 1; i < 8; ++i) m = fmaxf(m, acc[i]);
        out[(size_t)b * 256 + co] = fmaxf(m + bias[co], 0.f);
    }
}

// ---------------- FC head: (8,256) -> relu(128) -> 29 ----------------
__global__ void head_kernel(const float* __restrict__ v,
                            const float* __restrict__ fw1, const float* __restrict__ fb1,
                            const float* __restrict__ fw2, const float* __restrict__ fb2,
                            float* __restrict__ out) {
    int b = blockIdx.x, t = threadIdx.x;
    __shared__ float sv[256];
    __shared__ float s1[128];
    sv[t] = v[b * 256 + t];
    sv[t + 128] = v[b * 256 + t + 128];
    __syncthreads();
    float acc = fb1[t];
    const float* wr = fw1 + t * 256;
    for (int k = 0; k < 256; ++k) acc = fmaf(wr[k], sv[k], acc);
    s1[t] = fmaxf(acc, 0.f);
    __syncthreads();
    if (t < 29) {
        float a2 = fb2[t];
        const float* w2 = fw2 + t * 128;
        for (int k = 0; k < 128; ++k) a2 = fmaf(w2[k], s1[k], a2);
        out[b * 29 + t] = a2;
    }
}

extern "C" void kernel_launch(void* const* d_in, const int* in_sizes, int n_in,
                              void* d_out, int out_size, void* d_ws, size_t ws_size,
                              hipStream_t stream) {
    const float* x     = (const float*)d_in[0];
    const float* sigma = (const float*)d_in[1];
    const float* w1    = (const float*)d_in[2];
    const float* b1    = (const float*)d_in[3];
    const float* w2    = (const float*)d_in[4];
    const float* b2    = (const float*)d_in[5];
    const float* w3    = (const float*)d_in[6];
    const float* b3    = (const float*)d_in[7];
    const float* w4    = (const float*)d_in[8];
    const float* b4    = (const float*)d_in[9];
    const float* fw1   = (const float*)d_in[10];
    const float* fb1   = (const float*)d_in[11];
    const float* fw2   = (const float*)d_in[12];
    const float* fb2   = (const float*)d_in[13];
    float* out = (float*)d_out;

    float* A  = (float*)d_ws;          // 6,000,000 floats
    float* Bf = A + NVOX;              // 6,000,000 floats
    float* M0 = Bf + NVOX;             // 6*52*52
    float* M1 = M0 + NE * MP * MP;     // 6*52*52
    float* mx = M1 + NE * MP * MP;     // 1

    taps_kernel<<<1, 512, 0, stream>>>(sigma, M0, M1, mx);

    // separable blur as 3 per-plane 50x50 matmuls (scaled taps + global max in last)
    blur_mm<2, false><<<NB * NE * 50, 256, 0, stream>>>(x,  A,  M0, nullptr);
    blur_mm<1, false><<<NB * NE * 50, 256, 0, stream>>>(A,  Bf, M0, nullptr);
    blur_mm<0, true> <<<NB * NE * 50, 256, 0, stream>>>(Bf, A,  M1, mx);

    // conv1: (8,6,50^3) -> (8,32,24^3); COPT=8, 32 co/block; 2 phases x 3 ci
    conv_phase<8, 3, 2, 6, 50, 24, true, false><<<dim3(216, 1, 8), 256, 0, stream>>>(A, w1, b1, mx, Bf, 32);
    // conv2: (8,32,24^3) -> (8,64,11^3); COPT=4, 16 co/block; 8 phases x 4 ci
    conv_phase<4, 4, 8, 32, 24, 11, false, false><<<dim3(27, 4, 8), 256, 0, stream>>>(Bf, w2, b2, nullptr, A, 64);
    // conv3: (8,64,11^3) -> partials over 8 ci-chunks; COPT=4, 16 co/block
    float* part = Bf;                                  // 8*8*128*512 = 4,194,304 floats
    float* pooled3 = Bf + 8 * NB * 128 * 512;          // 8*128*64 floats
    conv_phase<4, 4, 2, 64, 11, 4, false, true><<<dim3(8, 8, 8), 256, 0, stream>>>(A, w3, b3, nullptr, part, 128);
    pool3_kernel<8><<<256, 256, 0, stream>>>(part, b3, pooled3);
    // conv4: (8,128,4^3) -> (8,256)  (write into A; conv3 input dead)
    float* v4 = A;
    conv4_kernel<<<512, 256, 0, stream>>>(pooled3, w4, b4, v4);
    // head
    head_kernel<<<8, 128, 0, stream>>>(v4, fw1, fb1, fw2, fb2, out);
}

// Round 9
// 473.643 us; speedup vs baseline: 1.1039x; 1.1039x over previous
//
#include <hip/hip_runtime.h>
#include <math.h>

#define DIMX 50
#define KK   51
#define NE   6
#define NB   8
#define NVOX ((size_t)NB * NE * DIMX * DIMX * DIMX)  // 6,000,000
#define MP   52                                      // padded M stride

// ---------------- taps + blur matrices: M[m][e][o][c] = tap_m,e[c-o+25] ----------------
__global__ void taps_kernel(const float* __restrict__ sigma,
                            float* __restrict__ M0,  // raw taps matrix  (NE*52*52)
                            float* __restrict__ M1,  // scaled taps matrix
                            float* __restrict__ maxval) {
    __shared__ float sg[NE * KK];
    __shared__ float sgs[NE * KK];
    __shared__ float ssum[NE];
    int t = threadIdx.x;
    if (t == 0) *maxval = 0.f;
    if (t < NE * KK) {
        int e = t / KK, i = t % KK;
        float d = (float)i - 25.0f;
        float var = sigma[e] * sigma[e];
        sg[t] = expf(-d * d / (2.f * var));
    }
    __syncthreads();
    if (t < NE) {
        float s = 0.f;
        for (int i = 0; i < KK; ++i) s += sg[t * KK + i];
        ssum[t] = s;
    }
    __syncthreads();
    if (t < NE * KK) {
        int e = t / KK;
        float S = 0.f;
        for (int e2 = 0; e2 < NE; ++e2) {
            float var2 = sigma[e2] * sigma[e2];
            float a2 = 1.f / (2.f * (float)M_PI * var2);
            float se = ssum[e2];
            S += a2 * se * se * se;
        }
        float var = sigma[e] * sigma[e];
        float a = 1.f / (2.f * (float)M_PI * var);
        sgs[t] = sg[t] * (a / S);
    }
    __syncthreads();
    for (int i = t; i < 2 * NE * MP * MP; i += 512) {
        int c = i % MP, o = (i / MP) % MP, e = (i / (MP * MP)) % NE, m = i / (MP * MP * NE);
        int j = c - o + 25;
        float v = 0.f;
        if (o < 50 && c < 50 && j >= 0 && j < KK) v = (m == 0 ? sg : sgs)[e * KK + j];
        (m == 0 ? M0 : M1)[(e * MP + o) * MP + c] = v;
    }
}

// ---------------- blur pass as per-plane 50x50 matmul ----------------
template <int AXIS, bool DOMAX>
__global__ __launch_bounds__(256, 8)
void blur_mm(const float* __restrict__ in, float* __restrict__ out,
             const float* __restrict__ M, float* __restrict__ maxval) {
    __shared__ float sp[50][MP];
    const int t  = threadIdx.x;
    const int f  = blockIdx.x % 50;
    const int be = blockIdx.x / 50;
    const int e  = be % NE;
    const float* base = in + (size_t)be * 125000;
    for (int i = t; i < 2500; i += 256) {
        int hi = i / 50, lo = i % 50;
        if (AXIS == 2)      sp[hi][lo] = base[hi * 2500 + f * 50 + lo];
        else if (AXIS == 1) sp[hi][lo] = base[f * 2500 + hi * 50 + lo];
        else                sp[lo][hi] = base[f * 2500 + hi * 50 + lo];
    }
    __syncthreads();
    const int lane = t & 63;
    const int lr   = lane < 50 ? lane : 49;
    const int wv   = __builtin_amdgcn_readfirstlane(t >> 6);
    float* ob = out + (size_t)be * 125000;
    const float* Me = M + (size_t)e * MP * MP;
    float m = 0.f;
    for (int g = wv; g < 13; g += 4) {
        const int o0 = g * 4;
        const float* Mr0 = Me + (o0 + 0) * MP;
        const float* Mr1 = Me + (o0 + 1) * MP;
        const float* Mr2 = Me + (o0 + 2) * MP;
        const float* Mr3 = Me + (o0 + 3) * MP;
        float a0 = 0.f, a1 = 0.f, a2 = 0.f, a3 = 0.f;
#pragma unroll 10
        for (int c = 0; c < 50; ++c) {
            float v = sp[c][lr];
            a0 = fmaf(Mr0[c], v, a0);
            a1 = fmaf(Mr1[c], v, a1);
            a2 = fmaf(Mr2[c], v, a2);
            a3 = fmaf(Mr3[c], v, a3);
        }
        if (lane < 50) {
            float accs[4] = {a0, a1, a2, a3};
#pragma unroll
            for (int k = 0; k < 4; ++k) {
                int o = o0 + k;
                if (o < 50) {
                    size_t addr;
                    if (AXIS == 2)      addr = (size_t)o * 2500 + f * 50 + lane;
                    else if (AXIS == 1) addr = (size_t)f * 2500 + o * 50 + lane;
                    else                addr = (size_t)f * 2500 + lane * 50 + o;
                    ob[addr] = accs[k];
                    if (DOMAX) m = fmaxf(m, accs[k]);
                }
            }
        }
    }
    if (DOMAX) {
        for (int o = 32; o; o >>= 1) m = fmaxf(m, __shfl_xor(m, o));
        if ((t & 63) == 0) atomicMax((int*)maxval, __float_as_int(m));
    }
}

// ---------------- fused conv3x3x3 [+pool2+bias+relu | partial], COPT co/thread ----------------
// Block: 4^3 pooled tile x (4*COPT) co. Window [10][10][12] staged via global_load_lds,
// double-buffered per phase. Per ci: FULL 4^3 window -> 64 VGPRs (paired b64 reads, one
// lgkmcnt drain), THEN c-loop of weight s_loads + FMAs with DS queue empty (pure-SMEM
// waits, hidden by TLP). Weights wave-uniform scalar loads.
template <int COPT, int NCI, int NPHASE, int CINTOT, int DIN, int DP, bool DIV, bool PARTIAL>
__global__ __launch_bounds__(256, 3)
void conv_reg(const float* __restrict__ in, const float* __restrict__ w,
              const float* __restrict__ bias, const float* __restrict__ maxval,
              float* __restrict__ out, int COUT) {
    constexpr int DIN3 = DIN * DIN * DIN;
    constexpr int NT   = (DP + 3) / 4;
    constexpr int NT3  = NT * NT * NT;
    constexpr int CWORDS = 1200;             // [10][10][12] per ci
    constexpr int NBUF = (NPHASE > 1) ? 2 : 1;
    __shared__ float swin[NBUF][NCI * CWORDS];

    const int t    = threadIdx.x;
    const int lane = t & 63;
    const int wave = __builtin_amdgcn_readfirstlane(t >> 6);
    const int px = lane & 3, py = (lane >> 2) & 3, pz = lane >> 4;

    const int tile  = blockIdx.x % NT3;
    const int chunk = blockIdx.x / NT3;
    const int tx = tile % NT, ty = (tile / NT) % NT, tz = tile / (NT * NT);
    const int b    = blockIdx.z;
    const int co0  = blockIdx.y * (4 * COPT) + wave * COPT;   // wave-uniform
    const int ci_base = chunk * NCI * NPHASE;

    const float* ib = in + ((size_t)b * CINTOT + ci_base) * DIN3;
    const float* wb = w + ((size_t)co0 * CINTOT + ci_base) * 27;
    const int ox0 = 8 * tx, oy0 = 8 * ty, oz0 = 8 * tz;

    // per-thread source offsets; LDS dest linear j = s*256 + t (no permutation)
    int off[5];
#pragma unroll
    for (int s = 0; s < 5; ++s) {
        int j = s * 256 + t; if (j >= CWORDS) j = CWORDS - 1;
        int z = j / 120, r = j % 120, y = r / 12, x = r % 12;
        if (x > 9) x = 9;
        int gz = oz0 + z; if (gz > DIN - 1) gz = DIN - 1;
        int gy = oy0 + y; if (gy > DIN - 1) gy = DIN - 1;
        int gx = ox0 + x; if (gx > DIN - 1) gx = DIN - 1;
        off[s] = (gz * DIN + gy) * DIN + gx;
    }

    auto stage = [&](int p, int bf) {
        const float* s0 = ib + (size_t)p * NCI * DIN3;
#pragma unroll
        for (int ci = 0; ci < NCI; ++ci) {
            const float* sc = s0 + (size_t)ci * DIN3;
            float* db = &swin[bf][ci * CWORDS];
#pragma unroll
            for (int s = 0; s < 4; ++s)
                __builtin_amdgcn_global_load_lds(
                    (const __attribute__((address_space(1))) void*)(sc + off[s]),
                    (__attribute__((address_space(3))) void*)(db + s * 256 + wave * 64),
                    4, 0, 0);
            if (t < CWORDS - 1024)
                __builtin_amdgcn_global_load_lds(
                    (const __attribute__((address_space(1))) void*)(sc + off[4]),
                    (__attribute__((address_space(3))) void*)(db + 1024 + wave * 64),
                    4, 0, 0);
        }
    };

    float acc[COPT][8];
#pragma unroll
    for (int c = 0; c < COPT; ++c)
#pragma unroll
        for (int i = 0; i < 8; ++i) acc[c][i] = 0.f;

    stage(0, 0);
    __syncthreads();

#pragma unroll 1
    for (int p = 0; p < NPHASE; ++p) {
        if (p + 1 < NPHASE) stage(p + 1, (p + 1) & 1);
        const float* pb = &swin[(NBUF > 1) ? (p & 1) : 0][0];
#pragma unroll 1
        for (int ci = 0; ci < NCI; ++ci) {
            const float* cb = pb + ci * CWORDS;
            // ---- full 4x4x4 window -> 64 VGPRs (paired b64 reads, one drain) ----
            float win[4][4][4];
#pragma unroll
            for (int dz = 0; dz < 4; ++dz)
#pragma unroll
                for (int dy = 0; dy < 4; ++dy) {
                    const float* rp = cb + (2 * pz + dz) * 120 + (2 * py + dy) * 12 + 2 * px;
                    float2 q0 = *(const float2*)(rp);
                    float2 q1 = *(const float2*)(rp + 2);
                    win[dz][dy][0] = q0.x; win[dz][dy][1] = q0.y;
                    win[dz][dy][2] = q1.x; win[dz][dy][3] = q1.y;
                }
            // ---- weights (pure SMEM from here) + FMA ----
#pragma unroll
            for (int c = 0; c < COPT; ++c) {
                const float* wc = wb + ((size_t)c * CINTOT + p * NCI + ci) * 27;
#pragma unroll
                for (int kz = 0; kz < 3; ++kz)
#pragma unroll
                    for (int ky = 0; ky < 3; ++ky)
#pragma unroll
                        for (int kx = 0; kx < 3; ++kx) {
                            float wv = wc[(kz * 3 + ky) * 3 + kx];
#pragma unroll
                            for (int oz = 0; oz < 2; ++oz)
#pragma unroll
                                for (int oy = 0; oy < 2; ++oy)
#pragma unroll
                                    for (int ox = 0; ox < 2; ++ox)
                                        acc[c][oz * 4 + oy * 2 + ox] =
                                            fmaf(wv, win[oz + kz][oy + ky][ox + kx],
                                                 acc[c][oz * 4 + oy * 2 + ox]);
                        }
            }
        }
        __syncthreads();
    }

    if constexpr (PARTIAL) {
#pragma unroll
        for (int c = 0; c < COPT; ++c) {
            size_t base = (((size_t)chunk * NB + b) * (size_t)COUT + (co0 + c)) * 512 + (size_t)lane * 8;
#pragma unroll
            for (int i = 0; i < 8; ++i) out[base + i] = acc[c][i];
        }
    } else {
        const int qx = tx * 4 + px, qy = ty * 4 + py, qz = tz * 4 + pz;
        if (qx < DP && qy < DP && qz < DP) {
            float mv = DIV ? *maxval : 1.f;
#pragma unroll
            for (int c = 0; c < COPT; ++c) {
                float m = acc[c][0];
#pragma unroll
                for (int i = 1; i < 8; ++i) m = fmaxf(m, acc[c][i]);
                float o = DIV ? (m / mv + bias[co0 + c]) : (m + bias[co0 + c]);
                out[((size_t)b * COUT + (co0 + c)) * (DP * DP * DP) + (qz * DP + qy) * DP + qx] =
                    fmaxf(o, 0.f);
            }
        }
    }
}

// ---------------- conv3 chunk-reduce + pool + bias + relu ----------------
template <int NCH>
__global__ void pool3_kernel(const float* __restrict__ part, const float* __restrict__ bias,
                             float* __restrict__ out) {
    int idx = blockIdx.x * 256 + threadIdx.x;  // 8*128*64
    if (idx >= NB * 128 * 64) return;
    int vox = idx & 63;
    int co  = (idx >> 6) & 127;
    int b   = idx >> 13;
    float s[8];
#pragma unroll
    for (int i = 0; i < 8; ++i) s[i] = 0.f;
#pragma unroll
    for (int ch = 0; ch < NCH; ++ch) {
        const float* p = part + (((size_t)ch * NB + b) * 128 + co) * 512 + (size_t)vox * 8;
#pragma unroll
        for (int i = 0; i < 8; ++i) s[i] += p[i];
    }
    float m = s[0];
#pragma unroll
    for (int i = 1; i < 8; ++i) m = fmaxf(m, s[i]);
    out[((size_t)b * 128 + co) * 64 + vox] = fmaxf(m + bias[co], 0.f);
}

// ---------------- conv4: Cin=128, Din=4 -> conv 2^3 -> pool 1; wave per (b,co) ----------------
__global__ void conv4_kernel(const float* __restrict__ in, const float* __restrict__ w,
                             const float* __restrict__ bias, float* __restrict__ out) {
    int wid = (int)((blockIdx.x * blockDim.x + threadIdx.x) >> 6);
    int lane = threadIdx.x & 63;
    if (wid >= NB * 256) return;
    int b = wid >> 8, co = wid & 255;
    float acc[8];
#pragma unroll
    for (int i = 0; i < 8; ++i) acc[i] = 0.f;
    for (int half = 0; half < 2; ++half) {
        int ci = lane + half * 64;
        const float* cb = in + ((size_t)b * 128 + ci) * 64;
        float win[64];
        const float4* c4 = (const float4*)cb;
#pragma unroll
        for (int i = 0; i < 16; ++i) {
            float4 v = c4[i];
            win[4 * i + 0] = v.x; win[4 * i + 1] = v.y;
            win[4 * i + 2] = v.z; win[4 * i + 3] = v.w;
        }
        const float* wc = w + ((size_t)co * 128 + ci) * 27;
        float wr[27];
#pragma unroll
        for (int i = 0; i < 27; ++i) wr[i] = wc[i];
#pragma unroll
        for (int kz = 0; kz < 3; ++kz)
#pragma unroll
            for (int ky = 0; ky < 3; ++ky)
#pragma unroll
                for (int kx = 0; kx < 3; ++kx) {
                    float wv = wr[(kz * 3 + ky) * 3 + kx];
#pragma unroll
                    for (int oz = 0; oz < 2; ++oz)
#pragma unroll
                        for (int oy = 0; oy < 2; ++oy)
#pragma unroll
                            for (int ox = 0; ox < 2; ++ox)
                                acc[(oz * 2 + oy) * 2 + ox] =
                                    fmaf(wv, win[((oz + kz) * 4 + (oy + ky)) * 4 + ox + kx],
                                         acc[(oz * 2 + oy) * 2 + ox]);
                }
    }
#pragma unroll
    for (int o = 32; o; o >>= 1)
#pragma unroll
        for (int i = 0; i < 8; ++i) acc[i] += __shfl_xor(acc[i], o);
    if (lane == 0) {
        float m = acc[0];
#pragma unroll
        for (int i = 1; i < 8; ++i) m = fmaxf(m, acc[i]);
        out[(size_t)b * 256 + co] = fmaxf(m + bias[co], 0.f);
    }
}

// ---------------- FC head: (8,256) -> relu(128) -> 29 ----------------
__global__ void head_kernel(const float* __restrict__ v,
                            const float* __restrict__ fw1, const float* __restrict__ fb1,
                            const float* __restrict__ fw2, const float* __restrict__ fb2,
                            float* __restrict__ out) {
    int b = blockIdx.x, t = threadIdx.x;
    __shared__ float sv[256];
    __shared__ float s1[128];
    sv[t] = v[b * 256 + t];
    sv[t + 128] = v[b * 256 + t + 128];
    __syncthreads();
    float acc = fb1[t];
    const float* wr = fw1 + t * 256;
    for (int k = 0; k < 256; ++k) acc = fmaf(wr[k], sv[k], acc);
    s1[t] = fmaxf(acc, 0.f);
    __syncthreads();
    if (t < 29) {
        float a2 = fb2[t];
        const float* w2 = fw2 + t * 128;
        for (int k = 0; k < 128; ++k) a2 = fmaf(w2[k], s1[k], a2);
        out[b * 29 + t] = a2;
    }
}

extern "C" void kernel_launch(void* const* d_in, const int* in_sizes, int n_in,
                              void* d_out, int out_size, void* d_ws, size_t ws_size,
                              hipStream_t stream) {
    const float* x     = (const float*)d_in[0];
    const float* sigma = (const float*)d_in[1];
    const float* w1    = (const float*)d_in[2];
    const float* b1    = (const float*)d_in[3];
    const float* w2    = (const float*)d_in[4];
    const float* b2    = (const float*)d_in[5];
    const float* w3    = (const float*)d_in[6];
    const float* b3    = (const float*)d_in[7];
    const float* w4    = (const float*)d_in[8];
    const float* b4    = (const float*)d_in[9];
    const float* fw1   = (const float*)d_in[10];
    const float* fb1   = (const float*)d_in[11];
    const float* fw2   = (const float*)d_in[12];
    const float* fb2   = (const float*)d_in[13];
    float* out = (float*)d_out;

    float* A  = (float*)d_ws;          // 6,000,000 floats
    float* Bf = A + NVOX;              // 6,000,000 floats
    float* M0 = Bf + NVOX;             // 6*52*52
    float* M1 = M0 + NE * MP * MP;     // 6*52*52
    float* mx = M1 + NE * MP * MP;     // 1

    taps_kernel<<<1, 512, 0, stream>>>(sigma, M0, M1, mx);

    // separable blur as 3 per-plane 50x50 matmuls (scaled taps + global max in last)
    blur_mm<2, false><<<NB * NE * 50, 256, 0, stream>>>(x,  A,  M0, nullptr);
    blur_mm<1, false><<<NB * NE * 50, 256, 0, stream>>>(A,  Bf, M0, nullptr);
    blur_mm<0, true> <<<NB * NE * 50, 256, 0, stream>>>(Bf, A,  M1, mx);

    // conv1: (8,6,50^3) -> (8,32,24^3); COPT=8, 32 co/block; 2 phases x 3 ci
    conv_reg<8, 3, 2, 6, 50, 24, true, false><<<dim3(216, 1, 8), 256, 0, stream>>>(A, w1, b1, mx, Bf, 32);
    // conv2: (8,32,24^3) -> (8,64,11^3); COPT=4, 16 co/block; 8 phases x 4 ci
    conv_reg<4, 4, 8, 32, 24, 11, false, false><<<dim3(27, 4, 8), 256, 0, stream>>>(Bf, w2, b2, nullptr, A, 64);
    // conv3: (8,64,11^3) -> partials over 8 ci-chunks; COPT=4, 16 co/block
    float* part = Bf;                                  // 8*8*128*512 = 4,194,304 floats
    float* pooled3 = Bf + 8 * NB * 128 * 512;          // 8*128*64 floats
    conv_reg<4, 4, 2, 64, 11, 4, false, true><<<dim3(8, 8, 8), 256, 0, stream>>>(A, w3, b3, nullptr, part, 128);
    pool3_kernel<8><<<256, 256, 0, stream>>>(part, b3, pooled3);
    // conv4: (8,128,4^3) -> (8,256)  (write into A; conv3 input dead)
    float* v4 = A;
    conv4_kernel<<<512, 256, 0, stream>>>(pooled3, w4, b4, v4);
    // head
    head_kernel<<<8, 128, 0, stream>>>(v4, fw1, fb1, fw2, fb2, out);
}

// Round 10
// 344.546 us; speedup vs baseline: 1.5175x; 1.3747x over previous
//
#include <hip/hip_runtime.h>
#include <math.h>

#define DIMX 50
#define KK   51
#define NE   6
#define NB   8
#define NVOX ((size_t)NB * NE * DIMX * DIMX * DIMX)  // 6,000,000
#define MP   52                                      // padded M stride

typedef short bf16x8 __attribute__((ext_vector_type(8)));
typedef float f32x4  __attribute__((ext_vector_type(4)));

__device__ __forceinline__ unsigned short f2bf(float f) {
    unsigned u = __float_as_uint(f);
    u += 0x7fffu + ((u >> 16) & 1u);      // RNE; inputs finite
    return (unsigned short)(u >> 16);
}

// ---------------- taps + blur matrices: M[m][e][o][c] = tap_m,e[c-o+25] ----------------
__global__ void taps_kernel(const float* __restrict__ sigma,
                            float* __restrict__ M0, float* __restrict__ M1,
                            float* __restrict__ maxval) {
    __shared__ float sg[NE * KK];
    __shared__ float sgs[NE * KK];
    __shared__ float ssum[NE];
    int t = threadIdx.x;
    if (t == 0) *maxval = 0.f;
    if (t < NE * KK) {
        int e = t / KK, i = t % KK;
        float d = (float)i - 25.0f;
        float var = sigma[e] * sigma[e];
        sg[t] = expf(-d * d / (2.f * var));
    }
    __syncthreads();
    if (t < NE) {
        float s = 0.f;
        for (int i = 0; i < KK; ++i) s += sg[t * KK + i];
        ssum[t] = s;
    }
    __syncthreads();
    if (t < NE * KK) {
        int e = t / KK;
        float S = 0.f;
        for (int e2 = 0; e2 < NE; ++e2) {
            float var2 = sigma[e2] * sigma[e2];
            float a2 = 1.f / (2.f * (float)M_PI * var2);
            float se = ssum[e2];
            S += a2 * se * se * se;
        }
        float var = sigma[e] * sigma[e];
        float a = 1.f / (2.f * (float)M_PI * var);
        sgs[t] = sg[t] * (a / S);
    }
    __syncthreads();
    for (int i = t; i < 2 * NE * MP * MP; i += 512) {
        int c = i % MP, o = (i / MP) % MP, e = (i / (MP * MP)) % NE, m = i / (MP * MP * NE);
        int j = c - o + 25;
        float v = 0.f;
        if (o < 50 && c < 50 && j >= 0 && j < KK) v = (m == 0 ? sg : sgs)[e * KK + j];
        (m == 0 ? M0 : M1)[(e * MP + o) * MP + c] = v;
    }
}

// ---------------- blur pass as per-plane 50x50 matmul ----------------
template <int AXIS, bool DOMAX>
__global__ __launch_bounds__(256, 8)
void blur_mm(const float* __restrict__ in, float* __restrict__ out,
             const float* __restrict__ M, float* __restrict__ maxval) {
    __shared__ float sp[50][MP];
    const int t  = threadIdx.x;
    const int f  = blockIdx.x % 50;
    const int be = blockIdx.x / 50;
    const int e  = be % NE;
    const float* base = in + (size_t)be * 125000;
    for (int i = t; i < 2500; i += 256) {
        int hi = i / 50, lo = i % 50;
        if (AXIS == 2)      sp[hi][lo] = base[hi * 2500 + f * 50 + lo];
        else if (AXIS == 1) sp[hi][lo] = base[f * 2500 + hi * 50 + lo];
        else                sp[lo][hi] = base[f * 2500 + hi * 50 + lo];
    }
    __syncthreads();
    const int lane = t & 63;
    const int lr   = lane < 50 ? lane : 49;
    const int wv   = __builtin_amdgcn_readfirstlane(t >> 6);
    float* ob = out + (size_t)be * 125000;
    const float* Me = M + (size_t)e * MP * MP;
    float m = 0.f;
    for (int g = wv; g < 13; g += 4) {
        const int o0 = g * 4;
        const float* Mr0 = Me + (o0 + 0) * MP;
        const float* Mr1 = Me + (o0 + 1) * MP;
        const float* Mr2 = Me + (o0 + 2) * MP;
        const float* Mr3 = Me + (o0 + 3) * MP;
        float a0 = 0.f, a1 = 0.f, a2 = 0.f, a3 = 0.f;
#pragma unroll 10
        for (int c = 0; c < 50; ++c) {
            float v = sp[c][lr];
            a0 = fmaf(Mr0[c], v, a0);
            a1 = fmaf(Mr1[c], v, a1);
            a2 = fmaf(Mr2[c], v, a2);
            a3 = fmaf(Mr3[c], v, a3);
        }
        if (lane < 50) {
            float accs[4] = {a0, a1, a2, a3};
#pragma unroll
            for (int k = 0; k < 4; ++k) {
                int o = o0 + k;
                if (o < 50) {
                    size_t addr;
                    if (AXIS == 2)      addr = (size_t)o * 2500 + f * 50 + lane;
                    else if (AXIS == 1) addr = (size_t)f * 2500 + o * 50 + lane;
                    else                addr = (size_t)f * 2500 + lane * 50 + o;
                    ob[addr] = accs[k];
                    if (DOMAX) m = fmaxf(m, accs[k]);
                }
            }
        }
    }
    if (DOMAX) {
        for (int o = 32; o; o >>= 1) m = fmaxf(m, __shfl_xor(m, o));
        if ((t & 63) == 0) atomicMax((int*)maxval, __float_as_int(m));
    }
}

// ---------------- T1: blur-out fp32 [b*6+e][z][y][x] -> X1 bf16 channels-last [b][z][y][x][16] ----------------
__global__ __launch_bounds__(256)
void t1_kernel(const float* __restrict__ A, unsigned short* __restrict__ X1) {
    const int z = blockIdx.x % 50, b = blockIdx.x / 50;
    const float* ab = A + (size_t)b * 6 * 125000 + z * 2500;
    unsigned short* xb = X1 + ((size_t)b * 125000 + (size_t)z * 2500) * 16;
    for (int i = threadIdx.x; i < 2500; i += 256) {
        unsigned short v[6];
#pragma unroll
        for (int e = 0; e < 6; ++e) v[e] = f2bf(ab[(size_t)e * 125000 + i]);
        uint4 q0, q1;
        q0.x = v[0] | ((unsigned)v[1] << 16);
        q0.y = v[2] | ((unsigned)v[3] << 16);
        q0.z = v[4] | ((unsigned)v[5] << 16);
        q0.w = 0u;
        q1.x = 0u; q1.y = 0u; q1.z = 0u; q1.w = 0u;
        *(uint4*)(xb + (size_t)i * 16)     = q0;
        *(uint4*)(xb + (size_t)i * 16 + 8) = q1;
    }
}

// ---------------- weight prep: generic B-fragment pack [cog][tap][ch][lane][8] ----------------
__global__ void wprep_kernel(const float* __restrict__ W, unsigned short* __restrict__ out,
                             int CIN, int NCH, int NCOG) {
    int idx = blockIdx.x * 256 + threadIdx.x;
    int total = NCOG * 27 * NCH * 64;
    if (idx >= total) return;
    int l = idx & 63;
    int r = idx >> 6;
    int ch = r % NCH; r /= NCH;
    int tap = r % 27;
    int cog = r / 27;
    int co = cog * 16 + (l & 15);
    unsigned short v[8];
#pragma unroll
    for (int j = 0; j < 8; ++j) {
        int ci = ch * 32 + (l >> 4) * 8 + j;
        v[j] = (ci < CIN) ? f2bf(W[((size_t)co * CIN + ci) * 27 + tap]) : (unsigned short)0;
    }
    uint4 q;
    q.x = v[0] | ((unsigned)v[1] << 16);
    q.y = v[2] | ((unsigned)v[3] << 16);
    q.z = v[4] | ((unsigned)v[5] << 16);
    q.w = v[6] | ((unsigned)v[7] << 16);
    ((uint4*)out)[idx] = q;
}

// ---------------- conv1 weight prep: dual-x-tap packing [cog][18][lane][8] ----------------
// K=32 = {x+0: ci 0..15, x+1: ci 0..15}. tg = (kz*3+ky)*2 + kxg.
// kxg=0: xsel0->kx0, xsel1->kx1.  kxg=1: xsel0->kx2, xsel1->zero.
__global__ void wprep1_kernel(const float* __restrict__ W, unsigned short* __restrict__ out) {
    int idx = blockIdx.x * 64 + threadIdx.x;
    if (idx >= 2 * 18 * 64) return;
    int l = idx & 63;
    int r = idx >> 6;
    int tg = r % 18;
    int cog = r / 18;
    int kzky = tg >> 1, kxg = tg & 1;
    int co = cog * 16 + (l & 15);
    unsigned short v[8];
#pragma unroll
    for (int j = 0; j < 8; ++j) {
        int k = (l >> 4) * 8 + j;
        int ci = k & 15, xsel = k >> 4;
        int kx = (kxg == 0) ? xsel : (xsel == 0 ? 2 : -1);
        float wv = 0.f;
        if (ci < 6 && kx >= 0) wv = W[((size_t)co * 6 + ci) * 27 + kzky * 3 + kx];
        v[j] = f2bf(wv);
    }
    uint4 q;
    q.x = v[0] | ((unsigned)v[1] << 16);
    q.y = v[2] | ((unsigned)v[3] << 16);
    q.z = v[4] | ((unsigned)v[5] << 16);
    q.w = v[6] | ((unsigned)v[7] << 16);
    ((uint4*)out)[idx] = q;
}

// ---------------- conv1 MFMA: X1[50^3][16] -> X2[24^3][32], /max + bias + pool + relu ----------------
// 1-wave blocks, 8 strips each. Strip = 16 conv-x  x 16 co, accs (cz,cy). 72 mfma/strip.
__global__ __launch_bounds__(64, 3)
void conv1_mfma(const unsigned short* __restrict__ X1, const unsigned short* __restrict__ wp1,
                const float* __restrict__ bias, const float* __restrict__ maxval,
                unsigned short* __restrict__ X2) {
    const int l = threadIdx.x, lm = l & 15, lg = l >> 4;
    const int s0 = blockIdx.x * 8;
    const int r0 = s0 / 72;                 // uniform in block (8 | 72)
    const int cog = r0 % 2;
    const int pz  = (r0 / 2) % 24;
    const int b   = r0 / 48;
    uint4 B[18];
    const uint4* wpb = (const uint4*)wp1 + cog * 18 * 64;
#pragma unroll
    for (int t = 0; t < 18; ++t) B[t] = wpb[t * 64 + l];
    const float rmv = 1.0f / (*maxval);
    const float bia = bias[cog * 16 + lm];
    const unsigned short* Xb = X1 + (size_t)b * 125000 * 16;
    const f32x4 z4 = {0.f, 0.f, 0.f, 0.f};
#pragma unroll 1
    for (int si = 0; si < 8; ++si) {
        const int sid = s0 + si;
        const int xs = sid % 3;
        const int py = (sid / 3) % 24;
        const int x0 = xs * 16;
        f32x4 acc[2][2];
#pragma unroll
        for (int cz = 0; cz < 2; ++cz)
#pragma unroll
            for (int cy = 0; cy < 2; ++cy) acc[cz][cy] = z4;
#pragma unroll
        for (int zi = 0; zi < 4; ++zi) {
            const int zin = 2 * pz + zi;
#pragma unroll
            for (int yi = 0; yi < 4; ++yi) {
                const int yin = 2 * py + yi;
                const unsigned short* rowb = Xb + (size_t)(zin * 50 + yin) * 50 * 16;
#pragma unroll
                for (int xg = 0; xg < 2; ++xg) {
                    bf16x8 a = *(const bf16x8*)(rowb + (x0 + 2 * xg + lm) * 16 + lg * 8);
#pragma unroll
                    for (int cz = 0; cz < 2; ++cz) {
                        const int kz = zi - cz;
                        if (kz < 0 || kz > 2) continue;
#pragma unroll
                        for (int cy = 0; cy < 2; ++cy) {
                            const int ky = yi - cy;
                            if (ky < 0 || ky > 2) continue;
                            const int tg = (kz * 3 + ky) * 2 + xg;
                            acc[cz][cy] = __builtin_amdgcn_mfma_f32_16x16x32_bf16(
                                a, *(const bf16x8*)&B[tg], acc[cz][cy], 0, 0, 0);
                        }
                    }
                }
            }
        }
        const int co = cog * 16 + lm;
#pragma unroll
        for (int ip = 0; ip < 2; ++ip) {
            float m0 = fmaxf(fmaxf(acc[0][0][2 * ip], acc[0][1][2 * ip]),
                             fmaxf(acc[1][0][2 * ip], acc[1][1][2 * ip]));
            float m1 = fmaxf(fmaxf(acc[0][0][2 * ip + 1], acc[0][1][2 * ip + 1]),
                             fmaxf(acc[1][0][2 * ip + 1], acc[1][1][2 * ip + 1]));
            float o = fmaxf(fmaxf(m0, m1) * rmv + bia, 0.f);
            int px = x0 / 2 + lg * 2 + ip;
            X2[((((size_t)b * 24 + pz) * 24 + py) * 24 + px) * 32 + co] = f2bf(o);
        }
    }
}

// ---------------- generic MFMA conv (conv2/conv3): bias + pool + relu -> bf16 ch-last ----------------
template <int DIN, int DP, int CI, int NCH, int NCOG, int NPY, int NXS, int SPB, int NPZ>
__global__ __launch_bounds__(64, 3)
void convN_mfma(const unsigned short* __restrict__ X, const unsigned short* __restrict__ wp,
                const float* __restrict__ bias, unsigned short* __restrict__ Y, int COUT) {
    const int l = threadIdx.x, lm = l & 15, lg = l >> 4;
    const int s0 = blockIdx.x * SPB;
    const int r0 = s0 / (NPY * NXS);        // uniform in block (SPB | NPY*NXS)
    const int cog = r0 % NCOG;
    const int pz  = (r0 / NCOG) % NPZ;
    const int b   = r0 / (NCOG * NPZ);
    const float bia = bias[cog * 16 + lm];
    const unsigned short* Xb = X + (size_t)b * DIN * DIN * DIN * CI;
    const uint4* wp4 = (const uint4*)wp;
    const f32x4 z4 = {0.f, 0.f, 0.f, 0.f};
#pragma unroll 1
    for (int si = 0; si < SPB; ++si) {
        const int sid = s0 + si;
        const int xs = sid % NXS;
        const int py = (sid / NXS) % NPY;
        const int x0 = xs * 16;
        int xo[3];
#pragma unroll
        for (int kx = 0; kx < 3; ++kx) {
            int xin = x0 + kx + lm;
            if (xin > DIN - 1) xin = DIN - 1;     // garbage rows masked at store
            xo[kx] = xin * CI + lg * 8;
        }
        f32x4 acc[2][2];
#pragma unroll
        for (int cz = 0; cz < 2; ++cz)
#pragma unroll
            for (int cy = 0; cy < 2; ++cy) acc[cz][cy] = z4;
#pragma unroll 1
        for (int ch = 0; ch < NCH; ++ch) {
            uint4 B[27];
            const uint4* wpb = wp4 + ((size_t)cog * 27 * NCH + ch) * 64;
#pragma unroll
            for (int t = 0; t < 27; ++t) B[t] = wpb[(size_t)t * NCH * 64 + l];
            const unsigned short* Xc = Xb + ch * 32;
#pragma unroll
            for (int zi = 0; zi < 4; ++zi) {
                const int zin = 2 * pz + zi;
#pragma unroll
                for (int yi = 0; yi < 4; ++yi) {
                    const int yin = 2 * py + yi;
                    const unsigned short* rowb = Xc + (size_t)(zin * DIN + yin) * DIN * CI;
#pragma unroll
                    for (int kx = 0; kx < 3; ++kx) {
                        bf16x8 a = *(const bf16x8*)(rowb + xo[kx]);
#pragma unroll
                        for (int cz = 0; cz < 2; ++cz) {
                            const int kz = zi - cz;
                            if (kz < 0 || kz > 2) continue;
#pragma unroll
                            for (int cy = 0; cy < 2; ++cy) {
                                const int ky = yi - cy;
                                if (ky < 0 || ky > 2) continue;
                                const int tap = (kz * 3 + ky) * 3 + kx;
                                acc[cz][cy] = __builtin_amdgcn_mfma_f32_16x16x32_bf16(
                                    a, *(const bf16x8*)&B[tap], acc[cz][cy], 0, 0, 0);
                            }
                        }
                    }
                }
            }
        }
        const int co = cog * 16 + lm;
#pragma unroll
        for (int ip = 0; ip < 2; ++ip) {
            float m0 = fmaxf(fmaxf(acc[0][0][2 * ip], acc[0][1][2 * ip]),
                             fmaxf(acc[1][0][2 * ip], acc[1][1][2 * ip]));
            float m1 = fmaxf(fmaxf(acc[0][0][2 * ip + 1], acc[0][1][2 * ip + 1]),
                             fmaxf(acc[1][0][2 * ip + 1], acc[1][1][2 * ip + 1]));
            float o = fmaxf(fmaxf(m0, m1) + bia, 0.f);
            int px = x0 / 2 + lg * 2 + ip;
            if (px < DP)
                Y[((((size_t)b * DP + pz) * DP + py) * DP + px) * COUT + co] = f2bf(o);
        }
    }
}

// ---------------- conv4: channels-last bf16 in, fp32 weights; wave per (b,co) ----------------
__global__ void conv4_kernel(const unsigned short* __restrict__ X4, const float* __restrict__ w,
                             const float* __restrict__ bias, float* __restrict__ out) {
    int wid = (int)((blockIdx.x * blockDim.x + threadIdx.x) >> 6);
    int lane = threadIdx.x & 63;
    if (wid >= NB * 256) return;
    int b = wid >> 8, co = wid & 255;
    float acc[8];
#pragma unroll
    for (int i = 0; i < 8; ++i) acc[i] = 0.f;
    for (int half = 0; half < 2; ++half) {
        int ci = lane + half * 64;
        float win[64];
#pragma unroll
        for (int v = 0; v < 64; ++v)
            win[v] = __uint_as_float((unsigned)X4[((size_t)b * 64 + v) * 128 + ci] << 16);
        const float* wc = w + ((size_t)co * 128 + ci) * 27;
        float wr[27];
#pragma unroll
        for (int i = 0; i < 27; ++i) wr[i] = wc[i];
#pragma unroll
        for (int kz = 0; kz < 3; ++kz)
#pragma unroll
            for (int ky = 0; ky < 3; ++ky)
#pragma unroll
                for (int kx = 0; kx < 3; ++kx) {
                    float wv = wr[(kz * 3 + ky) * 3 + kx];
#pragma unroll
                    for (int oz = 0; oz < 2; ++oz)
#pragma unroll
                        for (int oy = 0; oy < 2; ++oy)
#pragma unroll
                            for (int ox = 0; ox < 2; ++ox)
                                acc[(oz * 2 + oy) * 2 + ox] =
                                    fmaf(wv, win[((oz + kz) * 4 + (oy + ky)) * 4 + ox + kx],
                                         acc[(oz * 2 + oy) * 2 + ox]);
                }
    }
#pragma unroll
    for (int o = 32; o; o >>= 1)
#pragma unroll
        for (int i = 0; i < 8; ++i) acc[i] += __shfl_xor(acc[i], o);
    if (lane == 0) {
        float m = acc[0];
#pragma unroll
        for (int i = 1; i < 8; ++i) m = fmaxf(m, acc[i]);
        out[(size_t)b * 256 + co] = fmaxf(m + bias[co], 0.f);
    }
}

// ---------------- FC head: (8,256) -> relu(128) -> 29 ----------------
__global__ void head_kernel(const float* __restrict__ v,
                            const float* __restrict__ fw1, const float* __restrict__ fb1,
                            const float* __restrict__ fw2, const float* __restrict__ fb2,
                            float* __restrict__ out) {
    int b = blockIdx.x, t = threadIdx.x;
    __shared__ float sv[256];
    __shared__ float s1[128];
    sv[t] = v[b * 256 + t];
    sv[t + 128] = v[b * 256 + t + 128];
    __syncthreads();
    float acc = fb1[t];
    const float* wr = fw1 + t * 256;
    for (int k = 0; k < 256; ++k) acc = fmaf(wr[k], sv[k], acc);
    s1[t] = fmaxf(acc, 0.f);
    __syncthreads();
    if (t < 29) {
        float a2 = fb2[t];
        const float* w2 = fw2 + t * 128;
        for (int k = 0; k < 128; ++k) a2 = fmaf(w2[k], s1[k], a2);
        out[b * 29 + t] = a2;
    }
}

extern "C" void kernel_launch(void* const* d_in, const int* in_sizes, int n_in,
                              void* d_out, int out_size, void* d_ws, size_t ws_size,
                              hipStream_t stream) {
    const float* x     = (const float*)d_in[0];
    const float* sigma = (const float*)d_in[1];
    const float* w1    = (const float*)d_in[2];
    const float* b1    = (const float*)d_in[3];
    const float* w2    = (const float*)d_in[4];
    const float* b2    = (const float*)d_in[5];
    const float* w3    = (const float*)d_in[6];
    const float* b3    = (const float*)d_in[7];
    const float* w4    = (const float*)d_in[8];
    const float* b4    = (const float*)d_in[9];
    const float* fw1   = (const float*)d_in[10];
    const float* fb1   = (const float*)d_in[11];
    const float* fw2   = (const float*)d_in[12];
    const float* fb2   = (const float*)d_in[13];
    float* out = (float*)d_out;

    // ---- workspace layout (~65.3 MB) ----
    float* A = (float*)d_ws;                                  // 6,000,000 f
    unsigned short* X1 = (unsigned short*)(A + NVOX);         // 16,000,064 ush (incl. pad)
    float* Bf = (float*)X1;                                   // blur tmp overlays X1 (dead before T1)
    unsigned short* X2  = X1 + 16000064;                      // 3,538,944
    unsigned short* X3  = X2 + 3538944;                       // 681,472
    unsigned short* X4  = X3 + 681472;                        // 65,536
    unsigned short* wp1 = X4 + 65536;                         // 18,432
    unsigned short* wp2 = wp1 + 18432;                        // 55,296
    unsigned short* wp3 = wp2 + 55296;                        // 221,184
    float* M0 = (float*)(wp3 + 221184);
    float* M1 = M0 + NE * MP * MP;
    float* mx = M1 + NE * MP * MP;
    float* v4 = mx + 1;                                       // 2048 f

    taps_kernel<<<1, 512, 0, stream>>>(sigma, M0, M1, mx);

    // separable blur: 3 per-plane 50x50 matmuls (scaled taps + global max in last)
    blur_mm<2, false><<<NB * NE * 50, 256, 0, stream>>>(x,  A,  M0, nullptr);
    blur_mm<1, false><<<NB * NE * 50, 256, 0, stream>>>(A,  Bf, M0, nullptr);
    blur_mm<0, true> <<<NB * NE * 50, 256, 0, stream>>>(Bf, A,  M1, mx);

    // channels-last bf16 conversion + weight fragment packing
    t1_kernel<<<400, 256, 0, stream>>>(A, X1);
    wprep1_kernel<<<36, 64, 0, stream>>>(w1, wp1);
    wprep_kernel<<<27, 256, 0, stream>>>(w2, wp2, 32, 1, 4);
    wprep_kernel<<<108, 256, 0, stream>>>(w3, wp3, 64, 2, 8);

    // conv1: MFMA shift-GEMM, dual-x-tap K packing; strips 8*24*2*72 / 8 = 3456 blocks
    conv1_mfma<<<3456, 64, 0, stream>>>(X1, wp1, b1, mx, X2);
    // conv2: DIN24 DP11 CI32 NCH1 NCOG4 NPY11 NXS2 SPB2 NPZ11: 8*11*4*22/2 = 3872 blocks
    convN_mfma<24, 11, 32, 1, 4, 11, 2, 2, 11><<<3872, 64, 0, stream>>>(X2, wp2, b2, X3, 64);
    // conv3: DIN11 DP4 CI64 NCH2 NCOG8 NPY4 NXS1 SPB1 NPZ4: 8*4*8*4 = 1024 blocks
    convN_mfma<11, 4, 64, 2, 8, 4, 1, 1, 4><<<1024, 64, 0, stream>>>(X3, wp3, b3, X4, 128);

    // conv4 (VALU, channels-last bf16 in) + head
    conv4_kernel<<<512, 256, 0, stream>>>(X4, w4, b4, v4);
    head_kernel<<<8, 128, 0, stream>>>(v4, fw1, fb1, fw2, fb2, out);
}